// Round 8
// baseline (154.397 us; speedup 1.0000x reference)
//
#include <hip/hip_runtime.h>
#include <hip/hip_fp16.h>
#include <math.h>

#define Cc 32
#define Hc 128
#define Wc 160
#define Dc 48
#define HWc (Hc*Wc)
#define TS 16
#define HALO (TS+2)           // 18
#define NPOS (HALO*HALO)      // 324
#define DCHUNK 6
#define NCHUNK (Dc/DCHUNK)    // 8
#define NPASS 6               // ceil(NPOS / 64 quads)
#define NSLOT (DCHUNK+2)      // 8

// R18: cross-slice software pipeline. k_cost was ~60us across 8 variants with
// ALL pipes <30% -> barrier-lockstep exposed-latency. Now: var_l double-
// buffered; iteration dp = conv(dp,cur) INTERLEAVED with gather(dp+1 -> nxt),
// ONE barrier/slice. Gather loads issue early (2-deep Flight stagger), conv
// MFMA covers L2 latency. To fit dbuf in LDS: pad dropped (stride 4 float4 is
// conflict-free for the MFMA conv read: contiguous 1KB per wave) and
// parW/parI LDS eliminated (params computed quad-redundantly in the gather).
// LDS = 41472+8192+96 = 49.8KB -> 3 blocks/CU; DCHUNK=6 -> 640 blocks =
// 2.5/CU -> single fully-resident round. launch_bounds(256,1) (~200 VGPR).
// Spill guard: WRITE_SIZE must stay ~5.6MB.

typedef _Float16 h8v __attribute__((ext_vector_type(8)));
typedef float f32x4 __attribute__((ext_vector_type(4)));

union F4H { float4 f; __half2 h[4]; };
union PackCW { __half2 h[4]; float4 f; };
union AF { float4 f; h8v h; };

// ---------------- kernel 1: transpose CHW->HWC (fp32->fp16) + proj + weights + costvol zero ----------------
__global__ void k_pre(const float* __restrict__ f0, const float* __restrict__ f1,
                      const float* __restrict__ f2, const float* __restrict__ proj,
                      const float* __restrict__ wreg,
                      _Float16* __restrict__ o0, _Float16* __restrict__ o1, _Float16* __restrict__ o2,
                      float* __restrict__ wsproj, _Float16* __restrict__ w2h,
                      float* __restrict__ costvol) {
    const int tid = threadIdx.x;
    const int p = blockIdx.x * 256 + tid;
    if (blockIdx.y == 3) {
        // zero costvol for atomic accumulation (ws is poisoned 0xAA each call)
        if (p < HWc) {
#pragma unroll
            for (int d = 0; d < Dc; d++) costvol[d * HWc + p] = 0.f;
        }
        return;
    }
    if (p < HWc) {
        const float* f = (blockIdx.y == 0) ? f0 : (blockIdx.y == 1) ? f1 : f2;
        _Float16*    o = (blockIdx.y == 0) ? o0 : (blockIdx.y == 1) ? o1 : o2;
        float v[Cc];
#pragma unroll
        for (int c = 0; c < Cc; c++) v[c] = f[c * HWc + p];   // coalesced across lanes
        union { __half2 h[16]; float4 f4[4]; } rec;
#pragma unroll
        for (int c = 0; c < 16; c++) rec.h[c] = __floats2half2_rn(v[2 * c], v[2 * c + 1]);
        float4* o4 = (float4*)(o + (size_t)p * Cc);
#pragma unroll
        for (int j = 0; j < 4; j++) o4[j] = rec.f4[j];
    }
    if (blockIdx.x == 0 && blockIdx.y == 0) {
        // fp16 weight repack: w2h[khkw(9)][kd(3)][c(32)]
        for (int i = tid; i < 9 * 3 * Cc; i += 256) {
            int ch = i & 31;
            int t  = i >> 5;         // khkw*3 + kd
            int kd = t % 3;
            int khkw = t / 3;
            w2h[i] = (_Float16)wreg[ch * 27 + kd * 9 + khkw];
        }
        if (tid == 0) {
            float a[4][8];
            for (int i = 0; i < 4; i++)
                for (int j = 0; j < 4; j++) {
                    a[i][j]     = proj[i * 4 + j];
                    a[i][j + 4] = (i == j) ? 1.f : 0.f;
                }
            for (int col = 0; col < 4; col++) {
                int piv = col; float best = fabsf(a[col][col]);
                for (int r = col + 1; r < 4; r++) {
                    float v = fabsf(a[r][col]);
                    if (v > best) { best = v; piv = r; }
                }
                if (piv != col)
                    for (int j = 0; j < 8; j++) { float t = a[col][j]; a[col][j] = a[piv][j]; a[piv][j] = t; }
                float inv = 1.f / a[col][col];
                for (int j = 0; j < 8; j++) a[col][j] *= inv;
                for (int r = 0; r < 4; r++) if (r != col) {
                    float f = a[r][col];
                    for (int j = 0; j < 8; j++) a[r][j] -= f * a[col][j];
                }
            }
            for (int v = 1; v < 3; v++) {
                const float* P = proj + v * 16;
                float M[3][4];
                for (int i = 0; i < 3; i++)
                    for (int j = 0; j < 4; j++) {
                        float s = 0.f;
                        for (int k = 0; k < 4; k++) s += P[i * 4 + k] * a[k][4 + j];
                        M[i][j] = s;
                    }
                float* o = wsproj + (v - 1) * 12;
                o[0] = M[0][0]; o[1] = M[0][1]; o[2] = M[0][2];
                o[3] = M[1][0]; o[4] = M[1][1]; o[5] = M[1][2];
                o[6] = M[2][0]; o[7] = M[2][1]; o[8] = M[2][2];
                o[9] = M[0][3]; o[10] = M[1][3]; o[11] = M[2][3];
            }
        }
    }
}

// ---------------- kernel 2: pipelined warp + variance + MFMA conv ----------------
__global__ __launch_bounds__(256, 1) void k_cost(
    const _Float16* __restrict__ fT0, const _Float16* __restrict__ fT1,
    const _Float16* __restrict__ fT2, const float* __restrict__ dvals,
    const float4* __restrict__ w2h4, const float* __restrict__ wsproj,
    float* __restrict__ costvol)
{
    __shared__ float4 var_l[2][NPOS * 4];    // 41472 B double-buffered
    __shared__ float4 cost_l4[NSLOT * 64];   // 8192 B [slot][py][px/4]
    __shared__ float projl[24];
    float* cost_l = (float*)cost_l4;

    const int tid = threadIdx.x;
    if (tid < 24) projl[tid] = wsproj[tid];
#pragma unroll
    for (int i = 0; i < NSLOT; i++) cost_l[i * 256 + tid] = 0.f;
    __syncthreads();

    const int tileX = blockIdx.x;                 // 0..9
    const int tileY = blockIdx.y;                 // 0..7
    const int d0    = blockIdx.z * DCHUNK;
    const int baseH = tileY * TS - 1, baseW = tileX * TS - 1;

    const int posq = tid >> 2;                    // quad id: position within pass
    const int cc   = tid & 3;                     // float4 slot of 32-ch record

    const int wid  = tid >> 6;                    // wave 0..3
    const int lane = tid & 63;
    const int lrow = lane & 15;                   // A row offset / D col (kd)
    const int lsel = lane >> 4;                   // A k-slot / D row-block

    const float4* fT0_4 = (const float4*)fT0;
    const float4* fT1_4 = (const float4*)fT1;
    const float4* fT2_4 = (const float4*)fT2;

    // conv B-fragments (as R16, verified)
    h8v bfr[9];
    {
        const int kdc = (lrow < 3) ? lrow : 0;
#pragma unroll
        for (int t = 0; t < 9; t++) {
            AF u; u.f = w2h4[(t * 3 + kdc) * 4 + lsel];
            bfr[t] = u.h;
        }
    }

    // per-pass hoists: rays for THIS quad's position, ref index, validity
    float rx[NPASS][2], ry[NPASS][2], rz[NPASS][2];
    int   ref_i[NPASS];
    int   bmask = 0;
    float trn[2][3];
#pragma unroll
    for (int v = 0; v < 2; v++) {
        trn[v][0] = projl[v * 12 + 9];
        trn[v][1] = projl[v * 12 + 10];
        trn[v][2] = projl[v * 12 + 11];
    }
#pragma unroll
    for (int s = 0; s < NPASS; s++) {
        int p = posq + s * 64;
        bool act = p < NPOS;
        int pp = act ? p : 0;
        int py = pp / HALO, px = pp % HALO;
        int hyi = baseH + py, hxi = baseW + px;
        bool ok = act && hyi >= 0 && hyi < Hc && hxi >= 0 && hxi < Wc;
        if (ok) bmask |= (1 << s);
        ref_i[s] = (ok ? (hyi * Wc + hxi) : 0) * 4 + cc;
        float hx = (float)hxi, hy = (float)hyi;
#pragma unroll
        for (int v = 0; v < 2; v++) {
            const float* R = projl + v * 12;
            rx[s][v] = fmaf(R[0], hx, fmaf(R[1], hy, R[2]));
            ry[s][v] = fmaf(R[3], hx, fmaf(R[4], hy, R[5]));
            rz[s][v] = fmaf(R[6], hx, fmaf(R[7], hy, R[8]));
        }
    }

    struct Flight {
        float4 rf, t00, t01, t10, t11, u00, u01, u10, u11;   // 36 VGPR
        float4 pcf;                                          // packed fp16 weights
    };

    const __half2 kT3 = __float2half2_rn(1.f / 3.f);
    const __half2 kN9 = __float2half2_rn(-1.f / 9.f);

    // issue: compute bilinear params (quad-redundant) + fire all 9 loads
    auto issue = [&](int s, float depthN, Flight& F) {
        const bool ok = (bmask >> s) & 1;
        float cw[2][4]; int idx[2][4];
#pragma unroll
        for (int v = 0; v < 2; v++) {
            float X = fmaf(rx[s][v], depthN, trn[v][0]);
            float Y = fmaf(ry[s][v], depthN, trn[v][1]);
            float Z = fmaf(rz[s][v], depthN, trn[v][2]);
            float iz = 1.f / Z;
            float gx = X * iz, gy = Y * iz;
            float x0f = floorf(gx), y0f = floorf(gy);
            float wx = gx - x0f, wy = gy - y0f;
            int x0 = (int)x0f, y0 = (int)y0f;
            bool vx0 = (x0 >= 0) & (x0 <= Wc - 1);
            bool vx1 = (x0 >= -1) & (x0 <= Wc - 2);
            bool vy0 = (y0 >= 0) & (y0 <= Hc - 1);
            bool vy1 = (y0 >= -1) & (y0 <= Hc - 2);
            int xc0 = min(max(x0, 0), Wc - 1), xc1 = min(max(x0 + 1, 0), Wc - 1);
            int yc0 = min(max(y0, 0), Hc - 1), yc1 = min(max(y0 + 1, 0), Hc - 1);
            float ax = 1.f - wx, ay = 1.f - wy;
            cw[v][0] = (vx0 && vy0 && ok) ? ax * ay : 0.f;
            cw[v][1] = (vx1 && vy0 && ok) ? wx * ay : 0.f;
            cw[v][2] = (vx0 && vy1 && ok) ? ax * wy : 0.f;
            cw[v][3] = (vx1 && vy1 && ok) ? wx * wy : 0.f;
            idx[v][0] = (yc0 * Wc + xc0) * 4 + cc;
            idx[v][1] = (yc0 * Wc + xc1) * 4 + cc;
            idx[v][2] = (yc1 * Wc + xc0) * 4 + cc;
            idx[v][3] = (yc1 * Wc + xc1) * 4 + cc;
        }
        PackCW pc;
        pc.h[0] = __floats2half2_rn(cw[0][0], cw[0][1]);
        pc.h[1] = __floats2half2_rn(cw[0][2], cw[0][3]);
        pc.h[2] = __floats2half2_rn(cw[1][0], cw[1][1]);
        pc.h[3] = __floats2half2_rn(cw[1][2], cw[1][3]);
        F.pcf = pc.f;
        F.rf  = fT0_4[ref_i[s]];
        F.t00 = fT1_4[idx[0][0]]; F.t01 = fT1_4[idx[0][1]];
        F.t10 = fT1_4[idx[0][2]]; F.t11 = fT1_4[idx[0][3]];
        F.u00 = fT2_4[idx[1][0]]; F.u01 = fT2_4[idx[1][1]];
        F.u10 = fT2_4[idx[1][2]]; F.u11 = fT2_4[idx[1][3]];
    };

    // finish: variance math on landed loads, write var buffer
    auto finish = [&](int s, Flight& F, int nxt) {
        const bool ok = (bmask >> s) & 1;
        PackCW pc; pc.f = F.pcf;
        __half2 c0a = __low2half2(pc.h[0]), c0b = __high2half2(pc.h[0]);
        __half2 c0c = __low2half2(pc.h[1]), c0d = __high2half2(pc.h[1]);
        __half2 c1a = __low2half2(pc.h[2]), c1b = __high2half2(pc.h[2]);
        __half2 c1c = __low2half2(pc.h[3]), c1d = __high2half2(pc.h[3]);
        F4H rf; rf.f = ok ? F.rf : make_float4(0.f, 0.f, 0.f, 0.f);
        F4H t00, t01, t10, t11, u00, u01, u10, u11, vo;
        t00.f = F.t00; t01.f = F.t01; t10.f = F.t10; t11.f = F.t11;
        u00.f = F.u00; u01.f = F.u01; u10.f = F.u10; u11.f = F.u11;
#pragma unroll
        for (int j = 0; j < 4; j++) {
            __half2 a1 = __hfma2(c0a, t00.h[j], __hfma2(c0b, t01.h[j],
                         __hfma2(c0c, t10.h[j], __hmul2(c0d, t11.h[j]))));
            __half2 a2 = __hfma2(c1a, u00.h[j], __hfma2(c1b, u01.h[j],
                         __hfma2(c1c, u10.h[j], __hmul2(c1d, u11.h[j]))));
            __half2 r  = rf.h[j];
            __half2 sm = __hadd2(r, __hadd2(a1, a2));
            __half2 sq = __hfma2(r, r, __hfma2(a1, a1, __hmul2(a2, a2)));
            vo.h[j] = __hfma2(__hmul2(sm, sm), kN9, __hmul2(sq, kT3));
        }
        int p = posq + s * 64;
        if (p < NPOS) var_l[nxt][p * 4 + cc] = vo.f;
    };

    // conv group: 9 MFMAs for output row R, accumulate into LDS cost_l
    auto conv_g = [&](int g, int cur, int dp) {
        const int R = (wid << 2) + g;
        f32x4 acc = {0.f, 0.f, 0.f, 0.f};
#pragma unroll
        for (int t = 0; t < 9; t++) {
            const int dy = t / 3, dx = t % 3;
            AF a; a.f = var_l[cur][((R + dy) * HALO + dx + lrow) * 4 + lsel];
            acc = __builtin_amdgcn_mfma_f32_16x16x32_f16(a.h, bfr[t], acc, 0, 0, 0);
        }
        if (lrow < 3) {
            const int idx = ((dp - d0) + 2 - lrow) * 64 + R * 4 + lsel;
            float4 c = cost_l4[idx];
            c.x += acc[0]; c.y += acc[1]; c.z += acc[2]; c.w += acc[3];
            cost_l4[idx] = c;
        }
    };

    // ---- prologue: gather slice d0 into buf0 (2-deep stagger) ----
    {
        const float dN = dvals[d0];
        Flight fa, fb;
        issue(0, dN, fa); issue(1, dN, fb);
        finish(0, fa, 0); issue(2, dN, fa);
        finish(1, fb, 0); issue(3, dN, fb);
        finish(2, fa, 0); issue(4, dN, fa);
        finish(3, fb, 0); issue(5, dN, fb);
        finish(4, fa, 0); finish(5, fb, 0);
    }
    __syncthreads();

    const int dpLast = d0 + DCHUNK - 1;
    for (int dp = d0; dp <= dpLast; dp++) {
        const int cur = (dp - d0) & 1, nxt = cur ^ 1;
        if (dp < dpLast) {
            // conv(dp) interleaved with gather(dp+1): ONE barrier per slice
            const float dN = dvals[dp + 1];
            Flight fa, fb;
            issue(0, dN, fa); issue(1, dN, fb);
            conv_g(0, cur, dp);
            finish(0, fa, nxt); issue(2, dN, fa);
            conv_g(1, cur, dp);
            finish(1, fb, nxt); issue(3, dN, fb);
            conv_g(2, cur, dp);
            finish(2, fa, nxt); issue(4, dN, fa);
            conv_g(3, cur, dp);
            finish(3, fb, nxt); issue(5, dN, fb);
            finish(4, fa, nxt); finish(5, fb, nxt);
        } else {
            conv_g(0, cur, dp); conv_g(1, cur, dp);
            conv_g(2, cur, dp); conv_g(3, cur, dp);
        }
        __syncthreads();
    }

    // ---- epilogue: one coalesced atomicAdd pass, NSLOT slices/thread ----
    const int gy = tileY * TS + (tid >> 4), gx = tileX * TS + (tid & 15);
    float* cbase = costvol + gy * Wc + gx;
#pragma unroll
    for (int slot = 0; slot < NSLOT; slot++) {
        const int s = d0 + slot - 1;
        if (s >= 0 && s < Dc)
            atomicAdd(cbase + (size_t)s * HWc, cost_l[slot * 256 + tid]);
    }
}

// ---------------- kernel 3: softmax over depth + regression ----------------
__global__ void k_softmax(const float* __restrict__ costvol, const float* __restrict__ dvals,
                          const float* __restrict__ breg, float* __restrict__ out)
{
    const int px = blockIdx.x * 256 + threadIdx.x;
    if (px >= HWc) return;
    const float bias = breg[0];
    float c[Dc];
    float m = -1e30f;
#pragma unroll
    for (int d = 0; d < Dc; d++) {
        c[d] = costvol[d * HWc + px] + bias;
        m = fmaxf(m, c[d]);
    }
    float se = 0.f, sed = 0.f, me = 0.f;
#pragma unroll
    for (int d = 0; d < Dc; d++) {
        float e = __expf(c[d] - m);
        se += e;
        sed = fmaf(e, dvals[d], sed);
        me = fmaxf(me, e);
    }
    float inv = 1.f / se;
    out[px]       = sed * inv;   // depth
    out[HWc + px] = me * inv;    // photometric confidence
}

extern "C" void kernel_launch(void* const* d_in, const int* in_sizes, int n_in,
                              void* d_out, int out_size, void* d_ws, size_t ws_size,
                              hipStream_t stream) {
    const float* f0    = (const float*)d_in[0];
    const float* f1    = (const float*)d_in[1];
    const float* f2    = (const float*)d_in[2];
    const float* proj  = (const float*)d_in[3];
    const float* dvals = (const float*)d_in[4];
    const float* wreg  = (const float*)d_in[5];
    const float* breg  = (const float*)d_in[6];

    float* ws      = (float*)d_ws;
    float* wsproj  = ws;                         // 24 floats (pad to 32)
    _Float16* w2h  = (_Float16*)(ws + 32);       // 864 fp16 = 432 float slots
    _Float16* fT0h = (_Float16*)(ws + 32 + 432); // HWc*32 fp16 = 1.31MB each
    _Float16* fT1h = fT0h + (size_t)HWc * Cc;
    _Float16* fT2h = fT1h + (size_t)HWc * Cc;
    float* costvol = (float*)(fT2h + (size_t)HWc * Cc);  // Dc*HWc floats

    k_pre<<<dim3((HWc + 255) / 256, 4), 256, 0, stream>>>(f0, f1, f2, proj, wreg,
                                                          fT0h, fT1h, fT2h, wsproj, w2h,
                                                          costvol);

    dim3 grid(Wc / TS, Hc / TS, NCHUNK);   // 10 x 8 x 8 = 640 blocks of 256
    k_cost<<<grid, 256, 0, stream>>>(fT0h, fT1h, fT2h, dvals, (const float4*)w2h,
                                     wsproj, costvol);

    k_softmax<<<(HWc + 255) / 256, 256, 0, stream>>>(costvol, dvals, breg, (float*)d_out);
}

// Round 9
// 123.272 us; speedup vs baseline: 1.2525x; 1.2525x over previous
//
#include <hip/hip_runtime.h>
#include <hip/hip_fp16.h>
#include <math.h>

#define Cc 32
#define Hc 128
#define Wc 160
#define Dc 48
#define HWc (Hc*Wc)
#define TS 16
#define HALO (TS+2)           // 18
#define NPOS (HALO*HALO)      // 324
#define DCHUNK 8
#define NCHUNK (Dc/DCHUNK)    // 6
#define NPASS 6               // ceil(NPOS / 64 quads)
#define NSLOT (DCHUNK+2)      // 10

// R19: R17 base + statically-disambiguated var double-buffer (varA/varB) with
// the dp loop unrolled x2 by parity. PhaseB(t+1)->varB shares an interval with
// conv(t)<-varA (distinct arrays => compiler can interleave the gather's
// global loads under the conv's MFMA). phaseA(t+2) has its own tiny interval
// (par single-buffered, barrier-ordered). R18's failures fixed: no quad-
// redundant params, no Flight serialization, launch_bounds(256,2) keeps
// VGPR<=128. Pad dropped; XOR swizzle slot=(p<<2)+(c^((p>>1)&3)) keeps both
// the PhaseB write and the (single-slot-per-tap) MFMA conv read at 2
// lanes/bank = free (m136). MFMA conv makes the swizzle cheap (1 read/tap,
// unlike R12's 4xj runtime indexing). LDS 62176 <= 64KB; DCHUNK=8 -> grid
// 480 = single round at 2 blocks/CU (measured occ ~8 waves/CU anyway).
// Spill guard: WRITE_SIZE must stay ~5.6MB.

typedef _Float16 h8v __attribute__((ext_vector_type(8)));
typedef float f32x4 __attribute__((ext_vector_type(4)));

union F4H { float4 f; __half2 h[4]; };
union PackCW { __half2 h[4]; float4 f; };
union AF { float4 f; h8v h; };

// ---------------- kernel 1: transpose CHW->HWC (fp32->fp16) + proj + weights + costvol zero ----------------
__global__ void k_pre(const float* __restrict__ f0, const float* __restrict__ f1,
                      const float* __restrict__ f2, const float* __restrict__ proj,
                      const float* __restrict__ wreg,
                      _Float16* __restrict__ o0, _Float16* __restrict__ o1, _Float16* __restrict__ o2,
                      float* __restrict__ wsproj, _Float16* __restrict__ w2h,
                      float* __restrict__ costvol) {
    const int tid = threadIdx.x;
    const int p = blockIdx.x * 256 + tid;
    if (blockIdx.y == 3) {
        if (p < HWc) {
#pragma unroll
            for (int d = 0; d < Dc; d++) costvol[d * HWc + p] = 0.f;
        }
        return;
    }
    if (p < HWc) {
        const float* f = (blockIdx.y == 0) ? f0 : (blockIdx.y == 1) ? f1 : f2;
        _Float16*    o = (blockIdx.y == 0) ? o0 : (blockIdx.y == 1) ? o1 : o2;
        float v[Cc];
#pragma unroll
        for (int c = 0; c < Cc; c++) v[c] = f[c * HWc + p];   // coalesced across lanes
        union { __half2 h[16]; float4 f4[4]; } rec;
#pragma unroll
        for (int c = 0; c < 16; c++) rec.h[c] = __floats2half2_rn(v[2 * c], v[2 * c + 1]);
        float4* o4 = (float4*)(o + (size_t)p * Cc);
#pragma unroll
        for (int j = 0; j < 4; j++) o4[j] = rec.f4[j];
    }
    if (blockIdx.x == 0 && blockIdx.y == 0) {
        for (int i = tid; i < 9 * 3 * Cc; i += 256) {
            int ch = i & 31;
            int t  = i >> 5;         // khkw*3 + kd
            int kd = t % 3;
            int khkw = t / 3;
            w2h[i] = (_Float16)wreg[ch * 27 + kd * 9 + khkw];
        }
        if (tid == 0) {
            float a[4][8];
            for (int i = 0; i < 4; i++)
                for (int j = 0; j < 4; j++) {
                    a[i][j]     = proj[i * 4 + j];
                    a[i][j + 4] = (i == j) ? 1.f : 0.f;
                }
            for (int col = 0; col < 4; col++) {
                int piv = col; float best = fabsf(a[col][col]);
                for (int r = col + 1; r < 4; r++) {
                    float v = fabsf(a[r][col]);
                    if (v > best) { best = v; piv = r; }
                }
                if (piv != col)
                    for (int j = 0; j < 8; j++) { float t = a[col][j]; a[col][j] = a[piv][j]; a[piv][j] = t; }
                float inv = 1.f / a[col][col];
                for (int j = 0; j < 8; j++) a[col][j] *= inv;
                for (int r = 0; r < 4; r++) if (r != col) {
                    float f = a[r][col];
                    for (int j = 0; j < 8; j++) a[r][j] -= f * a[col][j];
                }
            }
            for (int v = 1; v < 3; v++) {
                const float* P = proj + v * 16;
                float M[3][4];
                for (int i = 0; i < 3; i++)
                    for (int j = 0; j < 4; j++) {
                        float s = 0.f;
                        for (int k = 0; k < 4; k++) s += P[i * 4 + k] * a[k][4 + j];
                        M[i][j] = s;
                    }
                float* o = wsproj + (v - 1) * 12;
                o[0] = M[0][0]; o[1] = M[0][1]; o[2] = M[0][2];
                o[3] = M[1][0]; o[4] = M[1][1]; o[5] = M[1][2];
                o[6] = M[2][0]; o[7] = M[2][1]; o[8] = M[2][2];
                o[9] = M[0][3]; o[10] = M[1][3]; o[11] = M[2][3];
            }
        }
    }
}

// ---------------- kernel 2: fused warp + variance + MFMA conv, pipelined dbuf ----------------
__global__ __launch_bounds__(256, 2) void k_cost(
    const _Float16* __restrict__ fT0, const _Float16* __restrict__ fT1,
    const _Float16* __restrict__ fT2, const float* __restrict__ dvals,
    const float4* __restrict__ w2h4, const float* __restrict__ wsproj,
    float* __restrict__ costvol)
{
    __shared__ float4 varA[NPOS * 4];        // 20736 B (XOR-swizzled slots)
    __shared__ float4 varB[NPOS * 4];        // 20736 B
    __shared__ float4 parW[NPOS];            // 5184 B
    __shared__ float4 parI[NPOS];            // 5184 B
    __shared__ float4 cost_l4[NSLOT * 64];   // 10240 B
    __shared__ float projl[24];
    float* cost_l = (float*)cost_l4;

    const int tid = threadIdx.x;
    if (tid < 24) projl[tid] = wsproj[tid];
#pragma unroll
    for (int i = 0; i < NSLOT; i++) cost_l[i * 256 + tid] = 0.f;
    __syncthreads();

    const int tileX = blockIdx.x;                 // 0..9
    const int tileY = blockIdx.y;                 // 0..7
    const int d0    = blockIdx.z * DCHUNK;
    const int baseH = tileY * TS - 1, baseW = tileX * TS - 1;

    const int posq = tid >> 2;                    // quad id: position within pass
    const int cc   = tid & 3;                     // float4 slot of 32-ch record

    const int wid  = tid >> 6;                    // wave 0..3
    const int lane = tid & 63;
    const int lrow = lane & 15;                   // A row offset / D col (kd)
    const int lsel = lane >> 4;                   // A k-slot / D row-block

    const float4* fT0_4 = (const float4*)fT0;
    const float4* fT1_4 = (const float4*)fT1;
    const float4* fT2_4 = (const float4*)fT2;

    // conv B-fragments (R16-verified layout)
    h8v bfr[9];
    {
        const int kdc = (lrow < 3) ? lrow : 0;
#pragma unroll
        for (int t = 0; t < 9; t++) {
            AF u; u.f = w2h4[(t * 3 + kdc) * 4 + lsel];
            bfr[t] = u.h;
        }
    }

    // ---- Phase A setup: thread owns positions tid, tid+256; rays hoisted ----
    float rAx[2][2], rAy[2][2], rAz[2][2];
    float trn[2][3];
#pragma unroll
    for (int v = 0; v < 2; v++) {
        trn[v][0] = projl[v * 12 + 9];
        trn[v][1] = projl[v * 12 + 10];
        trn[v][2] = projl[v * 12 + 11];
    }
    int amask = 0;
#pragma unroll
    for (int s = 0; s < 2; s++) {
        int p = tid + s * 256;
        bool act = p < NPOS;
        int pp = act ? p : 0;
        int py = pp / HALO, px = pp % HALO;
        int hyi = baseH + py, hxi = baseW + px;
        bool ok = act && hyi >= 0 && hyi < Hc && hxi >= 0 && hxi < Wc;
        if (ok) amask |= (1 << s);
        float hx = (float)hxi, hy = (float)hyi;
#pragma unroll
        for (int v = 0; v < 2; v++) {
            const float* R = projl + v * 12;
            rAx[s][v] = fmaf(R[0], hx, fmaf(R[1], hy, R[2]));
            rAy[s][v] = fmaf(R[3], hx, fmaf(R[4], hy, R[5]));
            rAz[s][v] = fmaf(R[6], hx, fmaf(R[7], hy, R[8]));
        }
    }

    // ---- Phase B setup: per-pass validity + hoisted ref taps ----
    int    bmask = 0;
    float4 rfv[NPASS];
#pragma unroll
    for (int s = 0; s < NPASS; s++) {
        int p = posq + s * 64;
        bool act = p < NPOS;
        int pp = act ? p : 0;
        int py = pp / HALO, px = pp % HALO;
        int hyi = baseH + py, hxi = baseW + px;
        bool ok = act && hyi >= 0 && hyi < Hc && hxi >= 0 && hxi < Wc;
        if (ok) bmask |= (1 << s);
        rfv[s] = ok ? fT0_4[(hyi * Wc + hxi) * 4 + cc] : make_float4(0.f, 0.f, 0.f, 0.f);
    }

    // ---- Phase A: bilinear params for slice dpn -> parW/parI ----
    auto phaseA = [&](int dpn) {
        const float depthN = dvals[dpn];
#pragma unroll
        for (int s = 0; s < 2; s++) {
            int p = tid + s * 256;
            if (p >= NPOS) break;
            if (!((amask >> s) & 1)) continue;
            float cw[2][4]; unsigned int pk[4];
#pragma unroll
            for (int v = 0; v < 2; v++) {
                float X = fmaf(rAx[s][v], depthN, trn[v][0]);
                float Y = fmaf(rAy[s][v], depthN, trn[v][1]);
                float Z = fmaf(rAz[s][v], depthN, trn[v][2]);
                float iz = 1.f / Z;
                float gx = X * iz, gy = Y * iz;
                float x0f = floorf(gx), y0f = floorf(gy);
                float wx = gx - x0f, wy = gy - y0f;
                int x0 = (int)x0f, y0 = (int)y0f;
                bool vx0 = (x0 >= 0) & (x0 <= Wc - 1);
                bool vx1 = (x0 + 1 >= 0) & (x0 + 1 <= Wc - 1);
                bool vy0 = (y0 >= 0) & (y0 <= Hc - 1);
                bool vy1 = (y0 + 1 >= 0) & (y0 + 1 <= Hc - 1);
                int xc0 = min(max(x0, 0), Wc - 1), xc1 = min(max(x0 + 1, 0), Wc - 1);
                int yc0 = min(max(y0, 0), Hc - 1), yc1 = min(max(y0 + 1, 0), Hc - 1);
                float ax = 1.f - wx, ay = 1.f - wy;
                cw[v][0] = (vx0 && vy0) ? ax * ay : 0.f;
                cw[v][1] = (vx1 && vy0) ? wx * ay : 0.f;
                cw[v][2] = (vx0 && vy1) ? ax * wy : 0.f;
                cw[v][3] = (vx1 && vy1) ? wx * wy : 0.f;
                unsigned int i0 = (unsigned int)(yc0 * Wc + xc0);
                unsigned int i1 = (unsigned int)(yc0 * Wc + xc1);
                unsigned int i2 = (unsigned int)(yc1 * Wc + xc0);
                unsigned int i3 = (unsigned int)(yc1 * Wc + xc1);
                pk[v * 2 + 0] = i0 | (i1 << 16);
                pk[v * 2 + 1] = i2 | (i3 << 16);
            }
            PackCW pc;
            pc.h[0] = __floats2half2_rn(cw[0][0], cw[0][1]);
            pc.h[1] = __floats2half2_rn(cw[0][2], cw[0][3]);
            pc.h[2] = __floats2half2_rn(cw[1][0], cw[1][1]);
            pc.h[3] = __floats2half2_rn(cw[1][2], cw[1][3]);
            parW[p] = pc.f;
            parI[p] = make_float4(__uint_as_float(pk[0]), __uint_as_float(pk[1]),
                                  __uint_as_float(pk[2]), __uint_as_float(pk[3]));
        }
    };

    const __half2 kT3 = __float2half2_rn(1.f / 3.f);
    const __half2 kN9 = __float2half2_rn(-1.f / 9.f);

    // ---- Phase B: gather + variance -> dst (XOR-swizzled slots) ----
    auto phaseB = [&](float4* dst) {
#pragma unroll
        for (int s = 0; s < NPASS; s++) {
            int p = posq + s * 64;
            if (p >= NPOS) continue;                 // only pass 5, posq>=4
            const int vaddr = (p << 2) + (cc ^ ((p >> 1) & 3));
            if (!((bmask >> s) & 1)) {
                dst[vaddr] = make_float4(0.f, 0.f, 0.f, 0.f);
                continue;
            }
            PackCW pc; pc.f = parW[p];               // quad-broadcast reads
            float4 pkf = parI[p];
            __half2 c0a = __low2half2(pc.h[0]), c0b = __high2half2(pc.h[0]);
            __half2 c0c = __low2half2(pc.h[1]), c0d = __high2half2(pc.h[1]);
            __half2 c1a = __low2half2(pc.h[2]), c1b = __high2half2(pc.h[2]);
            __half2 c1c = __low2half2(pc.h[3]), c1d = __high2half2(pc.h[3]);
            unsigned int u0 = __float_as_uint(pkf.x), u1 = __float_as_uint(pkf.y);
            unsigned int u2 = __float_as_uint(pkf.z), u3 = __float_as_uint(pkf.w);
            int i00 = u0 & 0xffff, i01 = u0 >> 16, i02 = u1 & 0xffff, i03 = u1 >> 16;
            int i10 = u2 & 0xffff, i11 = u2 >> 16, i12 = u3 & 0xffff, i13 = u3 >> 16;
            F4H rf; rf.f = rfv[s];
            F4H t00, t01, t10, t11, u00v, u01v, u10v, u11v, vo;
            t00.f = fT1_4[i00 * 4 + cc];
            t01.f = fT1_4[i01 * 4 + cc];
            t10.f = fT1_4[i02 * 4 + cc];
            t11.f = fT1_4[i03 * 4 + cc];
            u00v.f = fT2_4[i10 * 4 + cc];
            u01v.f = fT2_4[i11 * 4 + cc];
            u10v.f = fT2_4[i12 * 4 + cc];
            u11v.f = fT2_4[i13 * 4 + cc];
#pragma unroll
            for (int j = 0; j < 4; j++) {
                __half2 a1 = __hfma2(c0a, t00.h[j], __hfma2(c0b, t01.h[j],
                             __hfma2(c0c, t10.h[j], __hmul2(c0d, t11.h[j]))));
                __half2 a2 = __hfma2(c1a, u00v.h[j], __hfma2(c1b, u01v.h[j],
                             __hfma2(c1c, u10v.h[j], __hmul2(c1d, u11v.h[j]))));
                __half2 r  = rf.h[j];
                __half2 sm = __hadd2(r, __hadd2(a1, a2));
                __half2 sq = __hfma2(r, r, __hfma2(a1, a1, __hmul2(a2, a2)));
                vo.h[j] = __hfma2(__hmul2(sm, sm), kN9, __hmul2(sq, kT3));
            }
            dst[vaddr] = vo.f;
        }
    };

    // ---- conv on MFMA pipe from src buffer; accumulate into cost_l ----
    auto conv = [&](const float4* src, int dp) {
#pragma unroll
        for (int g = 0; g < 4; g++) {
            const int R = (wid << 2) + g;
            f32x4 acc = {0.f, 0.f, 0.f, 0.f};
#pragma unroll
            for (int t = 0; t < 9; t++) {
                const int dy = t / 3, dx = t % 3;
                const int pos = (R + dy) * HALO + dx + lrow;
                AF a; a.f = src[(pos << 2) + (lsel ^ ((pos >> 1) & 3))];
                acc = __builtin_amdgcn_mfma_f32_16x16x32_f16(a.h, bfr[t], acc, 0, 0, 0);
            }
            if (lrow < 3) {
                const int idx = ((dp - d0) + 2 - lrow) * 64 + R * 4 + lsel;
                float4 c = cost_l4[idx];
                c.x += acc[0]; c.y += acc[1]; c.z += acc[2]; c.w += acc[3];
                cost_l4[idx] = c;
            }
        }
    };

    const int dpLast = d0 + DCHUNK - 1;

    // ---- prologue ----
    phaseA(d0);
    __syncthreads();
    phaseB(varA);                 // gather slice d0 (unoverlapped, once)
    __syncthreads();
    phaseA(d0 + 1);
    __syncthreads();

    // ---- main loop: unrolled x2 by parity (static varA/varB) ----
    for (int i = 0; i < DCHUNK / 2; i++) {
        const int t = d0 + 2 * i;
        // interval A: gather(t+1)->varB overlapped with conv(t)<-varA
        phaseB(varB);
        conv(varA, t);
        __syncthreads();
        if (t + 2 <= dpLast) {    // interval B: params for t+2 (tiny)
            phaseA(t + 2);
            __syncthreads();
        }
        // interval A': gather(t+2)->varA overlapped with conv(t+1)<-varB
        if (t + 2 <= dpLast) phaseB(varA);
        conv(varB, t + 1);
        __syncthreads();
        if (t + 3 <= dpLast) {    // interval B': params for t+3
            phaseA(t + 3);
            __syncthreads();
        }
    }

    // ---- epilogue: one coalesced atomicAdd pass, NSLOT slices/thread ----
    const int gy = tileY * TS + (tid >> 4), gx = tileX * TS + (tid & 15);
    float* cbase = costvol + gy * Wc + gx;
#pragma unroll
    for (int slot = 0; slot < NSLOT; slot++) {
        const int s = d0 + slot - 1;
        if (s >= 0 && s < Dc)
            atomicAdd(cbase + (size_t)s * HWc, cost_l[slot * 256 + tid]);
    }
}

// ---------------- kernel 3: softmax over depth + regression ----------------
__global__ void k_softmax(const float* __restrict__ costvol, const float* __restrict__ dvals,
                          const float* __restrict__ breg, float* __restrict__ out)
{
    const int px = blockIdx.x * 256 + threadIdx.x;
    if (px >= HWc) return;
    const float bias = breg[0];
    float c[Dc];
    float m = -1e30f;
#pragma unroll
    for (int d = 0; d < Dc; d++) {
        c[d] = costvol[d * HWc + px] + bias;
        m = fmaxf(m, c[d]);
    }
    float se = 0.f, sed = 0.f, me = 0.f;
#pragma unroll
    for (int d = 0; d < Dc; d++) {
        float e = __expf(c[d] - m);
        se += e;
        sed = fmaf(e, dvals[d], sed);
        me = fmaxf(me, e);
    }
    float inv = 1.f / se;
    out[px]       = sed * inv;   // depth
    out[HWc + px] = me * inv;    // photometric confidence
}

extern "C" void kernel_launch(void* const* d_in, const int* in_sizes, int n_in,
                              void* d_out, int out_size, void* d_ws, size_t ws_size,
                              hipStream_t stream) {
    const float* f0    = (const float*)d_in[0];
    const float* f1    = (const float*)d_in[1];
    const float* f2    = (const float*)d_in[2];
    const float* proj  = (const float*)d_in[3];
    const float* dvals = (const float*)d_in[4];
    const float* wreg  = (const float*)d_in[5];
    const float* breg  = (const float*)d_in[6];

    float* ws      = (float*)d_ws;
    float* wsproj  = ws;                         // 24 floats (pad to 32)
    _Float16* w2h  = (_Float16*)(ws + 32);       // 864 fp16 = 432 float slots
    _Float16* fT0h = (_Float16*)(ws + 32 + 432); // HWc*32 fp16 = 1.31MB each
    _Float16* fT1h = fT0h + (size_t)HWc * Cc;
    _Float16* fT2h = fT1h + (size_t)HWc * Cc;
    float* costvol = (float*)(fT2h + (size_t)HWc * Cc);  // Dc*HWc floats

    k_pre<<<dim3((HWc + 255) / 256, 4), 256, 0, stream>>>(f0, f1, f2, proj, wreg,
                                                          fT0h, fT1h, fT2h, wsproj, w2h,
                                                          costvol);

    dim3 grid(Wc / TS, Hc / TS, NCHUNK);   // 10 x 8 x 6 = 480 blocks of 256
    k_cost<<<grid, 256, 0, stream>>>(fT0h, fT1h, fT2h, dvals, (const float4*)w2h,
                                     wsproj, costvol);

    k_softmax<<<(HWc + 255) / 256, 256, 0, stream>>>(costvol, dvals, breg, (float*)d_out);
}

// Round 10
// 118.376 us; speedup vs baseline: 1.3043x; 1.0414x over previous
//
#include <hip/hip_runtime.h>
#include <hip/hip_fp16.h>
#include <math.h>

#define Cc 32
#define Hc 128
#define Wc 160
#define Dc 48
#define HWc (Hc*Wc)
#define TSX 16
#define TSY 8
#define HALOX (TSX+2)         // 18
#define HALOY (TSY+2)         // 10
#define NPOS (HALOX*HALOY)    // 180
#define DCHUNK 8
#define NCHUNK (Dc/DCHUNK)    // 6
#define NPASS 3               // ceil(180 / 64 quads)
#define NSLOT (DCHUNK+2)      // 10

// R20: R19 structure (varA/varB static dbuf interleave, XOR swizzle, MFMA
// conv, LDS cost accum — all verified) with the tile split into 16x8 strips.
// R19 evidence: k_cost 48us, VALU 33%, occ 15.6% — latency-bound at 2
// blocks/CU (LDS 62.4KB). Strip halves NPOS 324->180: LDS 34016 B -> 4
// blocks/CU = 4 waves/SIMD (2x TLP), grid 10x16x6=960 = 3.75/CU single
// round. Cost: +11% gather positions/output. launch_bounds(256,4) caps
// VGPR at 128 (est ~90). Spill guard: WRITE_SIZE must stay ~5MB.

typedef _Float16 h8v __attribute__((ext_vector_type(8)));
typedef float f32x4 __attribute__((ext_vector_type(4)));

union F4H { float4 f; __half2 h[4]; };
union PackCW { __half2 h[4]; float4 f; };
union AF { float4 f; h8v h; };

// ---------------- kernel 1: transpose CHW->HWC (fp32->fp16) + proj + weights + costvol zero ----------------
__global__ void k_pre(const float* __restrict__ f0, const float* __restrict__ f1,
                      const float* __restrict__ f2, const float* __restrict__ proj,
                      const float* __restrict__ wreg,
                      _Float16* __restrict__ o0, _Float16* __restrict__ o1, _Float16* __restrict__ o2,
                      float* __restrict__ wsproj, _Float16* __restrict__ w2h,
                      float* __restrict__ costvol) {
    const int tid = threadIdx.x;
    const int p = blockIdx.x * 256 + tid;
    if (blockIdx.y == 3) {
        if (p < HWc) {
#pragma unroll
            for (int d = 0; d < Dc; d++) costvol[d * HWc + p] = 0.f;
        }
        return;
    }
    if (p < HWc) {
        const float* f = (blockIdx.y == 0) ? f0 : (blockIdx.y == 1) ? f1 : f2;
        _Float16*    o = (blockIdx.y == 0) ? o0 : (blockIdx.y == 1) ? o1 : o2;
        float v[Cc];
#pragma unroll
        for (int c = 0; c < Cc; c++) v[c] = f[c * HWc + p];   // coalesced across lanes
        union { __half2 h[16]; float4 f4[4]; } rec;
#pragma unroll
        for (int c = 0; c < 16; c++) rec.h[c] = __floats2half2_rn(v[2 * c], v[2 * c + 1]);
        float4* o4 = (float4*)(o + (size_t)p * Cc);
#pragma unroll
        for (int j = 0; j < 4; j++) o4[j] = rec.f4[j];
    }
    if (blockIdx.x == 0 && blockIdx.y == 0) {
        for (int i = tid; i < 9 * 3 * Cc; i += 256) {
            int ch = i & 31;
            int t  = i >> 5;         // khkw*3 + kd
            int kd = t % 3;
            int khkw = t / 3;
            w2h[i] = (_Float16)wreg[ch * 27 + kd * 9 + khkw];
        }
        if (tid == 0) {
            float a[4][8];
            for (int i = 0; i < 4; i++)
                for (int j = 0; j < 4; j++) {
                    a[i][j]     = proj[i * 4 + j];
                    a[i][j + 4] = (i == j) ? 1.f : 0.f;
                }
            for (int col = 0; col < 4; col++) {
                int piv = col; float best = fabsf(a[col][col]);
                for (int r = col + 1; r < 4; r++) {
                    float v = fabsf(a[r][col]);
                    if (v > best) { best = v; piv = r; }
                }
                if (piv != col)
                    for (int j = 0; j < 8; j++) { float t = a[col][j]; a[col][j] = a[piv][j]; a[piv][j] = t; }
                float inv = 1.f / a[col][col];
                for (int j = 0; j < 8; j++) a[col][j] *= inv;
                for (int r = 0; r < 4; r++) if (r != col) {
                    float f = a[r][col];
                    for (int j = 0; j < 8; j++) a[r][j] -= f * a[col][j];
                }
            }
            for (int v = 1; v < 3; v++) {
                const float* P = proj + v * 16;
                float M[3][4];
                for (int i = 0; i < 3; i++)
                    for (int j = 0; j < 4; j++) {
                        float s = 0.f;
                        for (int k = 0; k < 4; k++) s += P[i * 4 + k] * a[k][4 + j];
                        M[i][j] = s;
                    }
                float* o = wsproj + (v - 1) * 12;
                o[0] = M[0][0]; o[1] = M[0][1]; o[2] = M[0][2];
                o[3] = M[1][0]; o[4] = M[1][1]; o[5] = M[1][2];
                o[6] = M[2][0]; o[7] = M[2][1]; o[8] = M[2][2];
                o[9] = M[0][3]; o[10] = M[1][3]; o[11] = M[2][3];
            }
        }
    }
}

// ---------------- kernel 2: fused warp + variance + MFMA conv, strip-tiled dbuf pipeline ----------------
__global__ __launch_bounds__(256, 4) void k_cost(
    const _Float16* __restrict__ fT0, const _Float16* __restrict__ fT1,
    const _Float16* __restrict__ fT2, const float* __restrict__ dvals,
    const float4* __restrict__ w2h4, const float* __restrict__ wsproj,
    float* __restrict__ costvol)
{
    __shared__ float4 varA[NPOS * 4];        // 11520 B (XOR-swizzled slots)
    __shared__ float4 varB[NPOS * 4];        // 11520 B
    __shared__ float4 parW[NPOS];            // 2880 B
    __shared__ float4 parI[NPOS];            // 2880 B
    __shared__ float4 cost_l4[NSLOT * 32];   // 5120 B: [slot][R][lsel]
    __shared__ float projl[24];
    float* cost_l = (float*)cost_l4;

    const int tid = threadIdx.x;
    if (tid < 24) projl[tid] = wsproj[tid];
#pragma unroll
    for (int i = 0; i < 5; i++) cost_l[i * 256 + tid] = 0.f;   // 1280 floats
    __syncthreads();

    const int tileX = blockIdx.x;                 // 0..9
    const int sy    = blockIdx.y;                 // strip 0..15
    const int d0    = blockIdx.z * DCHUNK;
    const int baseH = sy * TSY - 1, baseW = tileX * TSX - 1;

    const int posq = tid >> 2;                    // quad id: position within pass
    const int cc   = tid & 3;                     // float4 slot of 32-ch record

    const int wid  = tid >> 6;                    // wave 0..3
    const int lane = tid & 63;
    const int lrow = lane & 15;                   // A row offset / D col (kd)
    const int lsel = lane >> 4;                   // A k-slot / D row-block

    const float4* fT0_4 = (const float4*)fT0;
    const float4* fT1_4 = (const float4*)fT1;
    const float4* fT2_4 = (const float4*)fT2;

    // conv B-fragments (R16-verified layout)
    h8v bfr[9];
    {
        const int kdc = (lrow < 3) ? lrow : 0;
#pragma unroll
        for (int t = 0; t < 9; t++) {
            AF u; u.f = w2h4[(t * 3 + kdc) * 4 + lsel];
            bfr[t] = u.h;
        }
    }

    // ---- Phase A setup: thread owns position tid (tid<NPOS); rays hoisted ----
    float rAx[2], rAy[2], rAz[2];
    float trn[2][3];
#pragma unroll
    for (int v = 0; v < 2; v++) {
        trn[v][0] = projl[v * 12 + 9];
        trn[v][1] = projl[v * 12 + 10];
        trn[v][2] = projl[v * 12 + 11];
    }
    bool aok;
    {
        int pp = (tid < NPOS) ? tid : 0;
        int py = pp / HALOX, px = pp % HALOX;
        int hyi = baseH + py, hxi = baseW + px;
        aok = (tid < NPOS) && hyi >= 0 && hyi < Hc && hxi >= 0 && hxi < Wc;
        float hx = (float)hxi, hy = (float)hyi;
#pragma unroll
        for (int v = 0; v < 2; v++) {
            const float* R = projl + v * 12;
            rAx[v] = fmaf(R[0], hx, fmaf(R[1], hy, R[2]));
            rAy[v] = fmaf(R[3], hx, fmaf(R[4], hy, R[5]));
            rAz[v] = fmaf(R[6], hx, fmaf(R[7], hy, R[8]));
        }
    }

    // ---- Phase B setup: per-pass validity + hoisted ref taps ----
    int    bmask = 0;
    float4 rfv[NPASS];
#pragma unroll
    for (int s = 0; s < NPASS; s++) {
        int p = posq + s * 64;
        bool act = p < NPOS;
        int pp = act ? p : 0;
        int py = pp / HALOX, px = pp % HALOX;
        int hyi = baseH + py, hxi = baseW + px;
        bool ok = act && hyi >= 0 && hyi < Hc && hxi >= 0 && hxi < Wc;
        if (ok) bmask |= (1 << s);
        rfv[s] = ok ? fT0_4[(hyi * Wc + hxi) * 4 + cc] : make_float4(0.f, 0.f, 0.f, 0.f);
    }

    // ---- Phase A: bilinear params for slice dpn -> parW/parI ----
    auto phaseA = [&](int dpn) {
        const float depthN = dvals[dpn];
        if (aok) {
            float cw[2][4]; unsigned int pk[4];
#pragma unroll
            for (int v = 0; v < 2; v++) {
                float X = fmaf(rAx[v], depthN, trn[v][0]);
                float Y = fmaf(rAy[v], depthN, trn[v][1]);
                float Z = fmaf(rAz[v], depthN, trn[v][2]);
                float iz = 1.f / Z;
                float gx = X * iz, gy = Y * iz;
                float x0f = floorf(gx), y0f = floorf(gy);
                float wx = gx - x0f, wy = gy - y0f;
                int x0 = (int)x0f, y0 = (int)y0f;
                bool vx0 = (x0 >= 0) & (x0 <= Wc - 1);
                bool vx1 = (x0 + 1 >= 0) & (x0 + 1 <= Wc - 1);
                bool vy0 = (y0 >= 0) & (y0 <= Hc - 1);
                bool vy1 = (y0 + 1 >= 0) & (y0 + 1 <= Hc - 1);
                int xc0 = min(max(x0, 0), Wc - 1), xc1 = min(max(x0 + 1, 0), Wc - 1);
                int yc0 = min(max(y0, 0), Hc - 1), yc1 = min(max(y0 + 1, 0), Hc - 1);
                float ax = 1.f - wx, ay = 1.f - wy;
                cw[v][0] = (vx0 && vy0) ? ax * ay : 0.f;
                cw[v][1] = (vx1 && vy0) ? wx * ay : 0.f;
                cw[v][2] = (vx0 && vy1) ? ax * wy : 0.f;
                cw[v][3] = (vx1 && vy1) ? wx * wy : 0.f;
                unsigned int i0 = (unsigned int)(yc0 * Wc + xc0);
                unsigned int i1 = (unsigned int)(yc0 * Wc + xc1);
                unsigned int i2 = (unsigned int)(yc1 * Wc + xc0);
                unsigned int i3 = (unsigned int)(yc1 * Wc + xc1);
                pk[v * 2 + 0] = i0 | (i1 << 16);
                pk[v * 2 + 1] = i2 | (i3 << 16);
            }
            PackCW pc;
            pc.h[0] = __floats2half2_rn(cw[0][0], cw[0][1]);
            pc.h[1] = __floats2half2_rn(cw[0][2], cw[0][3]);
            pc.h[2] = __floats2half2_rn(cw[1][0], cw[1][1]);
            pc.h[3] = __floats2half2_rn(cw[1][2], cw[1][3]);
            parW[tid] = pc.f;
            parI[tid] = make_float4(__uint_as_float(pk[0]), __uint_as_float(pk[1]),
                                    __uint_as_float(pk[2]), __uint_as_float(pk[3]));
        }
    };

    const __half2 kT3 = __float2half2_rn(1.f / 3.f);
    const __half2 kN9 = __float2half2_rn(-1.f / 9.f);

    // ---- Phase B: gather + variance -> dst (XOR-swizzled slots) ----
    auto phaseB = [&](float4* dst) {
#pragma unroll
        for (int s = 0; s < NPASS; s++) {
            int p = posq + s * 64;
            if (p >= NPOS) continue;                 // only pass 2, posq>=52
            const int vaddr = (p << 2) + (cc ^ ((p >> 1) & 3));
            if (!((bmask >> s) & 1)) {
                dst[vaddr] = make_float4(0.f, 0.f, 0.f, 0.f);
                continue;
            }
            PackCW pc; pc.f = parW[p];               // quad-broadcast reads
            float4 pkf = parI[p];
            __half2 c0a = __low2half2(pc.h[0]), c0b = __high2half2(pc.h[0]);
            __half2 c0c = __low2half2(pc.h[1]), c0d = __high2half2(pc.h[1]);
            __half2 c1a = __low2half2(pc.h[2]), c1b = __high2half2(pc.h[2]);
            __half2 c1c = __low2half2(pc.h[3]), c1d = __high2half2(pc.h[3]);
            unsigned int u0 = __float_as_uint(pkf.x), u1 = __float_as_uint(pkf.y);
            unsigned int u2 = __float_as_uint(pkf.z), u3 = __float_as_uint(pkf.w);
            int i00 = u0 & 0xffff, i01 = u0 >> 16, i02 = u1 & 0xffff, i03 = u1 >> 16;
            int i10 = u2 & 0xffff, i11 = u2 >> 16, i12 = u3 & 0xffff, i13 = u3 >> 16;
            F4H rf; rf.f = rfv[s];
            F4H t00, t01, t10, t11, u00v, u01v, u10v, u11v, vo;
            t00.f = fT1_4[i00 * 4 + cc];
            t01.f = fT1_4[i01 * 4 + cc];
            t10.f = fT1_4[i02 * 4 + cc];
            t11.f = fT1_4[i03 * 4 + cc];
            u00v.f = fT2_4[i10 * 4 + cc];
            u01v.f = fT2_4[i11 * 4 + cc];
            u10v.f = fT2_4[i12 * 4 + cc];
            u11v.f = fT2_4[i13 * 4 + cc];
#pragma unroll
            for (int j = 0; j < 4; j++) {
                __half2 a1 = __hfma2(c0a, t00.h[j], __hfma2(c0b, t01.h[j],
                             __hfma2(c0c, t10.h[j], __hmul2(c0d, t11.h[j]))));
                __half2 a2 = __hfma2(c1a, u00v.h[j], __hfma2(c1b, u01v.h[j],
                             __hfma2(c1c, u10v.h[j], __hmul2(c1d, u11v.h[j]))));
                __half2 r  = rf.h[j];
                __half2 sm = __hadd2(r, __hadd2(a1, a2));
                __half2 sq = __hfma2(r, r, __hfma2(a1, a1, __hmul2(a2, a2)));
                vo.h[j] = __hfma2(__hmul2(sm, sm), kN9, __hmul2(sq, kT3));
            }
            dst[vaddr] = vo.f;
        }
    };

    // ---- conv on MFMA pipe from src buffer; accumulate into cost_l ----
    // Each wave computes 2 output rows (R = wid*2+g) x 16 cols x 3 kd.
    auto conv = [&](const float4* src, int dp) {
#pragma unroll
        for (int g = 0; g < 2; g++) {
            const int R = (wid << 1) + g;                   // output row 0..7
            f32x4 acc = {0.f, 0.f, 0.f, 0.f};
#pragma unroll
            for (int t = 0; t < 9; t++) {
                const int dy = t / 3, dx = t % 3;
                const int pos = (R + dy) * HALOX + dx + lrow;
                AF a; a.f = src[(pos << 2) + (lsel ^ ((pos >> 1) & 3))];
                acc = __builtin_amdgcn_mfma_f32_16x16x32_f16(a.h, bfr[t], acc, 0, 0, 0);
            }
            if (lrow < 3) {
                const int idx = ((dp - d0) + 2 - lrow) * 32 + R * 4 + lsel;
                float4 c = cost_l4[idx];
                c.x += acc[0]; c.y += acc[1]; c.z += acc[2]; c.w += acc[3];
                cost_l4[idx] = c;
            }
        }
    };

    const int dpLast = d0 + DCHUNK - 1;

    // ---- prologue ----
    phaseA(d0);
    __syncthreads();
    phaseB(varA);                 // gather slice d0 (unoverlapped, once)
    __syncthreads();
    phaseA(d0 + 1);
    __syncthreads();

    // ---- main loop: unrolled x2 by parity (static varA/varB) ----
    for (int i = 0; i < DCHUNK / 2; i++) {
        const int t = d0 + 2 * i;
        // interval A: gather(t+1)->varB overlapped with conv(t)<-varA
        phaseB(varB);
        conv(varA, t);
        __syncthreads();
        if (t + 2 <= dpLast) {    // interval B: params for t+2 (tiny)
            phaseA(t + 2);
            __syncthreads();
        }
        // interval A': gather(t+2)->varA overlapped with conv(t+1)<-varB
        if (t + 2 <= dpLast) phaseB(varA);
        conv(varB, t + 1);
        __syncthreads();
        if (t + 3 <= dpLast) {    // interval B': params for t+3
            phaseA(t + 3);
            __syncthreads();
        }
    }

    // ---- epilogue: one coalesced atomicAdd pass, 5 slots per thread ----
    const int c    = tid & 127;                   // cell: (R = c>>4, col = c&15)
    const int half = tid >> 7;                    // slots half*5 .. half*5+4
    const int gy = sy * TSY + (c >> 4), gx = tileX * TSX + (c & 15);
    float* cbase = costvol + gy * Wc + gx;
#pragma unroll
    for (int k = 0; k < 5; k++) {
        const int slot = half * 5 + k;
        const int s = d0 + slot - 1;
        if (s >= 0 && s < Dc)
            atomicAdd(cbase + (size_t)s * HWc, cost_l[slot * 128 + c]);
    }
}

// ---------------- kernel 3: softmax over depth + regression ----------------
__global__ void k_softmax(const float* __restrict__ costvol, const float* __restrict__ dvals,
                          const float* __restrict__ breg, float* __restrict__ out)
{
    const int px = blockIdx.x * 256 + threadIdx.x;
    if (px >= HWc) return;
    const float bias = breg[0];
    float c[Dc];
    float m = -1e30f;
#pragma unroll
    for (int d = 0; d < Dc; d++) {
        c[d] = costvol[d * HWc + px] + bias;
        m = fmaxf(m, c[d]);
    }
    float se = 0.f, sed = 0.f, me = 0.f;
#pragma unroll
    for (int d = 0; d < Dc; d++) {
        float e = __expf(c[d] - m);
        se += e;
        sed = fmaf(e, dvals[d], sed);
        me = fmaxf(me, e);
    }
    float inv = 1.f / se;
    out[px]       = sed * inv;   // depth
    out[HWc + px] = me * inv;    // photometric confidence
}

extern "C" void kernel_launch(void* const* d_in, const int* in_sizes, int n_in,
                              void* d_out, int out_size, void* d_ws, size_t ws_size,
                              hipStream_t stream) {
    const float* f0    = (const float*)d_in[0];
    const float* f1    = (const float*)d_in[1];
    const float* f2    = (const float*)d_in[2];
    const float* proj  = (const float*)d_in[3];
    const float* dvals = (const float*)d_in[4];
    const float* wreg  = (const float*)d_in[5];
    const float* breg  = (const float*)d_in[6];

    float* ws      = (float*)d_ws;
    float* wsproj  = ws;                         // 24 floats (pad to 32)
    _Float16* w2h  = (_Float16*)(ws + 32);       // 864 fp16 = 432 float slots
    _Float16* fT0h = (_Float16*)(ws + 32 + 432); // HWc*32 fp16 = 1.31MB each
    _Float16* fT1h = fT0h + (size_t)HWc * Cc;
    _Float16* fT2h = fT1h + (size_t)HWc * Cc;
    float* costvol = (float*)(fT2h + (size_t)HWc * Cc);  // Dc*HWc floats

    k_pre<<<dim3((HWc + 255) / 256, 4), 256, 0, stream>>>(f0, f1, f2, proj, wreg,
                                                          fT0h, fT1h, fT2h, wsproj, w2h,
                                                          costvol);

    dim3 grid(Wc / TSX, Hc / TSY, NCHUNK);   // 10 x 16 x 6 = 960 blocks of 256
    k_cost<<<grid, 256, 0, stream>>>(fT0h, fT1h, fT2h, dvals, (const float4*)w2h,
                                     wsproj, costvol);

    k_softmax<<<(HWc + 255) / 256, 256, 0, stream>>>(costvol, dvals, breg, (float*)d_out);
}